// Round 2
// baseline (10280.069 us; speedup 1.0000x reference)
//
#include <hip/hip_runtime.h>
#include <hip/hip_bf16.h>

// ============================================================================
// CompILE forward: B=256, T=128, V=512, H=256, L=64, S=4
// Round 2: LSTM rewritten as 64-block cooperative kernel, W_hh in registers,
// h exchanged via enc_b + agent-scope flags (no LDS, no per-step W streaming).
// ============================================================================
#define RNG_VARIANT 2

typedef __attribute__((ext_vector_type(8))) short bf16x8;
typedef __attribute__((ext_vector_type(4))) float f32x4;

// ---------------------------------------------------------------- helpers ---
__host__ __device__ inline void tf2x32(unsigned k0, unsigned k1,
                                       unsigned x0, unsigned x1,
                                       unsigned* r0, unsigned* r1) {
  unsigned ks2 = k0 ^ k1 ^ 0x1BD11BDAu;
#define TFR(r) { x0 += x1; x1 = (x1 << r) | (x1 >> (32 - r)); x1 ^= x0; }
  x0 += k0; x1 += k1;
  TFR(13) TFR(15) TFR(26) TFR(6)  x0 += k1;  x1 += ks2 + 1u;
  TFR(17) TFR(29) TFR(16) TFR(24) x0 += ks2; x1 += k0 + 2u;
  TFR(13) TFR(15) TFR(26) TFR(6)  x0 += k0;  x1 += k1 + 3u;
  TFR(17) TFR(29) TFR(16) TFR(24) x0 += k1;  x1 += ks2 + 4u;
  TFR(13) TFR(15) TFR(26) TFR(6)  x0 += ks2; x1 += k0 + 5u;
#undef TFR
  *r0 = x0; *r1 = x1;
}

__device__ __forceinline__ unsigned rng_bits32(unsigned k0, unsigned k1,
                                               unsigned n, unsigned half) {
#if RNG_VARIANT == 2
  unsigned o0, o1; tf2x32(k0, k1, 0u, n, &o0, &o1); return o0 ^ o1;
#elif RNG_VARIANT == 1
  unsigned o0, o1; tf2x32(k0, k1, 0u, n, &o0, &o1); return o1;
#else
  unsigned i0 = (n < half) ? n : n - half;
  unsigned o0, o1; tf2x32(k0, k1, i0, i0 + half, &o0, &o1);
  return (n < half) ? o0 : o1;
#endif
}

__device__ __forceinline__ float bits_to_unit(unsigned bits) {
  return __uint_as_float((bits >> 9) | 0x3f800000u) - 1.0f;
}

__device__ __forceinline__ unsigned short f2bf(float x) {
  union { float f; unsigned u; } v; v.f = x;
  unsigned r = v.u + 0x7fffu + ((v.u >> 16) & 1u);  // RNE
  return (unsigned short)(r >> 16);
}
__device__ __forceinline__ float bf2f(unsigned short h) {
  return __uint_as_float(((unsigned)h) << 16);
}

__device__ __forceinline__ float sigm(float x) {
  return 1.0f / (1.0f + __expf(-x));
}
__device__ __forceinline__ float tanh_f(float x) {
  float ax = fabsf(x);
  float e = __expf(-2.0f * ax);
  float t = (1.0f - e) / (1.0f + e);
  return copysignf(t, x);
}

// XLA ErfInv32 (Giles), w = -log1p(-x*x)
__device__ __forceinline__ float erfinv_f(float x) {
  float w = -log1pf(-x * x);
  float p;
  if (w < 5.0f) {
    w -= 2.5f;
    p = 2.81022636e-08f;
    p = fmaf(p, w, 3.43273939e-07f);
    p = fmaf(p, w, -3.5233877e-06f);
    p = fmaf(p, w, -4.39150654e-06f);
    p = fmaf(p, w, 0.00021858087f);
    p = fmaf(p, w, -0.00125372503f);
    p = fmaf(p, w, -0.00417768164f);
    p = fmaf(p, w, 0.246640727f);
    p = fmaf(p, w, 1.50140941f);
  } else {
    w = sqrtf(w) - 3.0f;
    p = -0.000200214257f;
    p = fmaf(p, w, 0.000100950558f);
    p = fmaf(p, w, 0.00134934322f);
    p = fmaf(p, w, -0.00367342844f);
    p = fmaf(p, w, 0.00573950773f);
    p = fmaf(p, w, -0.0076224613f);
    p = fmaf(p, w, 0.00943887047f);
    p = fmaf(p, w, 1.00167406f);
    p = fmaf(p, w, 2.83297682f);
  }
  return p * x;
}

// ------------------------------------------------------------- prep/embed ---
__global__ void prep_k(const float* __restrict__ w_ih, const float* __restrict__ w_hh,
                       const float* __restrict__ wb1, const float* __restrict__ b_ih,
                       const float* __restrict__ b_hh,
                       unsigned short* __restrict__ wih_b, unsigned short* __restrict__ wpk,
                       unsigned short* __restrict__ wb1_b, float* __restrict__ biasg,
                       unsigned int* __restrict__ flags) {
  int i = blockIdx.x * 256 + threadIdx.x;            // 65536 threads
  for (int idx = i; idx < 262144; idx += 65536) wih_b[idx] = f2bf(w_ih[idx]);
  if (i < 65536) wb1_b[i] = f2bf(wb1[i]);
  if (i < 1024) biasg[i] = b_ih[i] + b_hh[i];
  if (i < 16) flags[i] = 0u;
  if (i < 32768) {
    int l = i & 63, ks = (i >> 6) & 7, tile = i >> 9;
    int n = tile * 16 + (l & 15);
    int kb = ks * 32 + (l >> 4) * 8;
    const float* src = w_hh + (size_t)n * 256 + kb;
#pragma unroll
    for (int j = 0; j < 8; ++j) wpk[(size_t)i * 8 + j] = f2bf(src[j]);
  }
}

__global__ void embed_k(const int* __restrict__ inputs, const float* __restrict__ embw,
                        unsigned short* __restrict__ emb) {
  int bt = blockIdx.x, h = threadIdx.x;
  emb[(size_t)bt * 256 + h] = f2bf(embw[(size_t)inputs[bt] * 256 + h]);
}

// ------------------------------------------------------------------- GEMM ---
__global__ __launch_bounds__(256) void gemm_bf16(
    const unsigned short* __restrict__ A, const unsigned short* __restrict__ Bt,
    const float* __restrict__ bias, float* __restrict__ outF,
    unsigned short* __restrict__ outB, int M, int N, int K, int relu) {
  __shared__ __align__(16) unsigned short As[128][40];
  __shared__ __align__(16) unsigned short Bs[128][40];
  int tid = threadIdx.x;
  int m0 = blockIdx.x * 128, n0 = blockIdx.y * 128;
  int w = tid >> 6, l = tid & 63;
  int wr = w >> 1, wc = w & 1;
  int lr = l & 15, lq = l >> 4;
  f32x4 acc[4][4];
#pragma unroll
  for (int i = 0; i < 4; ++i)
#pragma unroll
    for (int j = 0; j < 4; ++j) acc[i][j] = (f32x4)(0.0f);
  int sr = tid >> 2, sk = (tid & 3) * 8;
#pragma unroll 1
  for (int kc = 0; kc < K; kc += 32) {
#pragma unroll
    for (int p = 0; p < 2; ++p) {
      int row = sr + p * 64;
      *(bf16x8*)&As[row][sk] = *(const bf16x8*)(A + (size_t)(m0 + row) * K + kc + sk);
      *(bf16x8*)&Bs[row][sk] = *(const bf16x8*)(Bt + (size_t)(n0 + row) * K + kc + sk);
    }
    __syncthreads();
    bf16x8 af[4], bfr[4];
#pragma unroll
    for (int i = 0; i < 4; ++i) {
      af[i] = *(const bf16x8*)&As[wr * 64 + i * 16 + lr][lq * 8];
      bfr[i] = *(const bf16x8*)&Bs[wc * 64 + i * 16 + lr][lq * 8];
    }
#pragma unroll
    for (int i = 0; i < 4; ++i)
#pragma unroll
      for (int j = 0; j < 4; ++j)
        acc[i][j] = __builtin_amdgcn_mfma_f32_16x16x32_bf16(af[i], bfr[j], acc[i][j], 0, 0, 0);
    __syncthreads();
  }
#pragma unroll
  for (int i = 0; i < 4; ++i)
#pragma unroll
    for (int j = 0; j < 4; ++j) {
      int col = n0 + wc * 64 + j * 16 + lr;
      float bv = bias ? bias[col] : 0.0f;
#pragma unroll
      for (int q = 0; q < 4; ++q) {
        int row = m0 + wr * 64 + i * 16 + lq * 4 + q;
        float v = acc[i][j][q] + bv;
        if (relu) v = fmaxf(v, 0.0f);
        size_t o = (size_t)row * N + col;
        if (outF) outF[o] = v;
        if (outB) outB[o] = f2bf(v);
      }
    }
}

// ------------------------------------------------------------------- LSTM ---
// 64 blocks = 16 row-groups x 4 col-blocks. Block (rg,cb): rows rg*16..+16,
// h-cols cb*64..+64 (gate cols {g*256 + cb*64 + w*16 + lr}, g=0..3).
// W slice held entirely in registers (128 VGPR/lane). h exchanged via enc_b
// (bf16, also an output staging buffer) + per-row-group monotonic flag at
// agent scope. No LDS, no __syncthreads; 16 waves/rg sync via flag >= 16*t.
template <bool XWF32>
__global__ __launch_bounds__(256, 1) void lstm_reg(
    const unsigned short* __restrict__ Wpk, const void* __restrict__ xw_,
    const float* __restrict__ mask_buf, int use_mask,
    float* __restrict__ enc_out, unsigned short* __restrict__ enc_b,
    unsigned int* flags, unsigned int flag_base) {
  const int tid = threadIdx.x;
  const int w = tid >> 6, l = tid & 63;
  const int lr = l & 15, lq = l >> 4;
  const int rg = blockIdx.x >> 2, cb = blockIdx.x & 3;
  const int b0 = rg * 16;
  const int coln = cb * 64 + w * 16 + lr;   // h column this thread covers

  // ---- W tiles -> registers: gate g uses packed tile (g*16 + cb*4 + w) ----
  bf16x8 Wr[4][8];
#pragma unroll
  for (int g = 0; g < 4; ++g) {
    const unsigned short* bp = Wpk + (size_t)(g * 16 + cb * 4 + w) * 4096;
#pragma unroll
    for (int ks = 0; ks < 8; ++ks)
      Wr[g][ks] = *(const bf16x8*)(bp + ks * 512 + l * 8);
  }

  float cst[4] = {0.f, 0.f, 0.f, 0.f};
  unsigned int* flag = flags + rg;

  float xwp[4][4];
  float mvp[4];
  const float* xwf = (const float*)xw_;
  const unsigned short* xwb = (const unsigned short*)xw_;

  // prefetch xw + mask for step t into registers
#define PREFETCH(T)                                                          \
  {                                                                          \
    _Pragma("unroll") for (int g = 0; g < 4; ++g) {                          \
      int n = g * 256 + coln;                                                \
      _Pragma("unroll") for (int q = 0; q < 4; ++q) {                        \
        size_t ro = ((size_t)(b0 + lq * 4 + q) * 128 + (T)) * 1024 + n;      \
        xwp[g][q] = XWF32 ? xwf[ro] : bf2f(xwb[ro]);                         \
      }                                                                      \
    }                                                                        \
    _Pragma("unroll") for (int q = 0; q < 4; ++q)                            \
        mvp[q] = use_mask ? mask_buf[(b0 + lq * 4 + q) * 128 + (T)] : 1.0f;  \
  }

  PREFETCH(0);

#pragma unroll 1
  for (int t = 0; t < 128; ++t) {
    f32x4 acc[4];
    float mv[4];
#pragma unroll
    for (int g = 0; g < 4; ++g)
#pragma unroll
      for (int q = 0; q < 4; ++q) acc[g][q] = xwp[g][q];
#pragma unroll
    for (int q = 0; q < 4; ++q) mv[q] = mvp[q];

    if (t < 127) PREFETCH(t + 1);  // issue next-step loads before the spin

    if (t > 0) {
      unsigned thr = flag_base + 16u * (unsigned)t;
      while (__hip_atomic_load(flag, __ATOMIC_RELAXED, __HIP_MEMORY_SCOPE_AGENT) < thr)
        __builtin_amdgcn_s_sleep(1);
      __threadfence();  // acquire: invalidate so h reads see peers' writes
      const unsigned short* hrow =
          enc_b + ((size_t)(b0 + lr) * 128 + (t - 1)) * 256;
      bf16x8 af[8];
#pragma unroll
      for (int ks = 0; ks < 8; ++ks)
        af[ks] = *(const bf16x8*)(hrow + ks * 32 + lq * 8);
#pragma unroll
      for (int ks = 0; ks < 8; ++ks)
#pragma unroll
        for (int g = 0; g < 4; ++g)
          acc[g] = __builtin_amdgcn_mfma_f32_16x16x32_bf16(af[ks], Wr[g][ks],
                                                           acc[g], 0, 0, 0);
    }

    // activations + store h slice (f32 enc output + bf16 exchange/staging)
#pragma unroll
    for (int q = 0; q < 4; ++q) {
      float ig = acc[0][q], fg = acc[1][q], gg = acc[2][q], og = acc[3][q];
      float cn = sigm(fg) * cst[q] + sigm(ig) * tanh_f(gg);
      float hv = sigm(og) * tanh_f(cn);
      hv *= mv[q];
      cn *= mv[q];
      cst[q] = cn;
      size_t eo = ((size_t)(b0 + lq * 4 + q) * 128 + t) * 256 + coln;
      enc_out[eo] = hv;
      enc_b[eo] = f2bf(hv);
    }

    __threadfence();  // release: drain stores + write back before flagging
    if (l == 0)
      __hip_atomic_fetch_add(flag, 1u, __ATOMIC_RELAXED, __HIP_MEMORY_SCOPE_AGENT);
  }
#undef PREFETCH
}

// ------------------------------------------------------------------- GEMV ---
__global__ __launch_bounds__(512) void gemv_lb(const unsigned short* __restrict__ hid,
                                               const float* __restrict__ wb2,
                                               const float* __restrict__ bb2,
                                               float* __restrict__ lb) {
  int l = threadIdx.x & 63, w = threadIdx.x >> 6;
  int row = blockIdx.x * 8 + w;
  const unsigned short* hp = hid + (size_t)row * 256 + l * 4;
  uint2 hv = *(const uint2*)hp;
  float4 wv = *(const float4*)(wb2 + l * 4);
  float s = bf2f((unsigned short)(hv.x & 0xffff)) * wv.x +
            bf2f((unsigned short)(hv.x >> 16)) * wv.y +
            bf2f((unsigned short)(hv.y & 0xffff)) * wv.z +
            bf2f((unsigned short)(hv.y >> 16)) * wv.w;
#pragma unroll
  for (int d = 32; d > 0; d >>= 1) s += __shfl_xor(s, d);
  if (l == 0) lb[row] = s + bb2[0];
}

// --------------------------------------------------------------- boundary ---
__global__ __launch_bounds__(128) void boundary_k(
    const float* __restrict__ lb, int seg, unsigned k0, unsigned k1,
    float* __restrict__ blog, float* __restrict__ bsamp, float* __restrict__ masks_o,
    float* __restrict__ lca, float* __restrict__ maskb) {
  int b = blockIdx.x, t = threadIdx.x;
  int l = t & 63, w = t >> 6;
  float v = lb[b * 128 + t];
  if (t == 0) v = -1e30f;
  unsigned bits = rng_bits32(k0, k1, (unsigned)(b * 128 + t), 16384u);
  float u = bits_to_unit(bits);
  float g = -logf(1e-17f - logf(u + 1e-17f));
  float y = v + g;  // TEMP_B = 1
  float m = y;
#pragma unroll
  for (int d = 32; d > 0; d >>= 1) m = fmaxf(m, __shfl_xor(m, d));
  __shared__ float xs[2];
  if (l == 0) xs[w] = m;
  __syncthreads();
  m = fmaxf(xs[0], xs[1]);
  float e = expf(y - m);
  float ssum = e;
#pragma unroll
  for (int d = 32; d > 0; d >>= 1) ssum += __shfl_xor(ssum, d);
  __shared__ float ss2[2];
  if (l == 0) ss2[w] = ssum;
  __syncthreads();
  ssum = ss2[0] + ss2[1];
  float sb = e / ssum;
  blog[b * 128 + t] = v;
  bsamp[b * 128 + t] = sb;
  float cs = sb;
#pragma unroll
  for (int d = 1; d < 64; d <<= 1) {
    float p = __shfl_up(cs, d);
    if (l >= d) cs += p;
  }
  __shared__ float wt[2];
  if (l == 63) wt[w] = cs;
  __syncthreads();
  if (w == 1) cs += wt[0];
  float lg = logf(cs + 1e-17f);
  float a = (seg == 0 ? 0.0f : lca[b * 128 + t]) + lg;
  lca[b * 128 + t] = a;
  float mk = expf(a);
  maskb[b * 128 + t] = mk;
  masks_o[b * 128 + t] = mk;
}

__global__ __launch_bounds__(128) void onehot_k(const int* __restrict__ lengths,
                                                float* __restrict__ bsamp) {
  int b = blockIdx.x, t = threadIdx.x;
  bsamp[b * 128 + t] = (t == lengths[b] - 1) ? 1.0f : 0.0f;
}

// ---------------------------------------------------------------- readout ---
__global__ __launch_bounds__(256) void readout_k(const float* __restrict__ enc,
                                                 const float* __restrict__ sb,
                                                 float* __restrict__ rout) {
  int b = blockIdx.x, h = threadIdx.x;
  __shared__ float sl[128];
  if (h < 128) sl[h] = sb[b * 128 + h];
  __syncthreads();
  float a = 0.0f;
  const float* ep = enc + (size_t)b * 128 * 256 + h;
#pragma unroll 4
  for (int t2 = 0; t2 < 127; ++t2) a += ep[(size_t)t2 * 256] * sl[t2 + 1];
  rout[b * 256 + h] = a;
}

// ----------------------------------------------------------------- z head ---
__global__ __launch_bounds__(128) void zhead_k(
    const float* __restrict__ rout, const float* __restrict__ wz1,
    const float* __restrict__ bz1, const float* __restrict__ wz2,
    const float* __restrict__ bz2, unsigned k0, unsigned k1,
    float* __restrict__ zlo, float* __restrict__ zsa, float* __restrict__ zbuf) {
  int b = blockIdx.x, t = threadIdx.x;
  __shared__ float rl[256], hz[256], lzs[128];
  rl[t] = rout[b * 256 + t];
  rl[t + 128] = rout[b * 256 + t + 128];
  __syncthreads();
  for (int h = t; h < 256; h += 128) {
    float a = bz1[h];
    const float* wp = wz1 + (size_t)h * 256;
    for (int k2 = 0; k2 < 256; ++k2) a += rl[k2] * wp[k2];
    hz[h] = fmaxf(a, 0.0f);
  }
  __syncthreads();
  {
    float a = bz2[t];
    const float* wp = wz2 + (size_t)t * 256;
    for (int k2 = 0; k2 < 256; ++k2) a += hz[k2] * wp[k2];
    zlo[b * 128 + t] = a;
    lzs[t] = a;
  }
  __syncthreads();
  if (t < 64) {
    unsigned bits = rng_bits32(k0, k1, (unsigned)(b * 64 + t), 8192u);
    float f = bits_to_unit(bits);
    const float LO = -0x1.fffffep-1f;
    float u = fmaxf(LO, f * 2.0f + LO);
    float ez = 1.4142135623730951f * erfinv_f(u);
    float z = lzs[t] + expf(0.5f * lzs[t + 64]) * ez;
    zsa[b * 64 + t] = z;
    zbuf[b * 64 + t] = z;
  }
}

// ----------------------------------------------------------------- decode ---
__global__ __launch_bounds__(256) void decode_k(
    const float* __restrict__ zbuf, const float* __restrict__ wd1,
    const float* __restrict__ bd1, const float* __restrict__ wd2,
    const float* __restrict__ bd2, float* __restrict__ pred) {
  int b = blockIdx.x, t = threadIdx.x;
  __shared__ float zl[64], hd[256];
  if (t < 64) zl[t] = zbuf[b * 64 + t];
  __syncthreads();
  {
    float a = bd1[t];
    const float* wp = wd1 + (size_t)t * 64;
    for (int k2 = 0; k2 < 64; ++k2) a += zl[k2] * wp[k2];
    hd[t] = fmaxf(a, 0.0f);
  }
  __syncthreads();
  for (int v2 = t; v2 < 512; v2 += 256) {
    float p = bd2[v2];
    const float* wp = wd2 + (size_t)v2 * 256;
    for (int k2 = 0; k2 < 256; ++k2) p += hd[k2] * wp[k2];
    pred[b * 512 + v2] = p;
  }
}

__global__ __launch_bounds__(128) void bcast_k(const float* __restrict__ pred,
                                               float* __restrict__ recs) {
  int bt = blockIdx.x;
  int b = bt >> 7;
  float4 v = ((const float4*)(pred + (size_t)b * 512))[threadIdx.x];
  ((float4*)(recs + (size_t)bt * 512))[threadIdx.x] = v;
}

// ------------------------------------------------------------------- host ---
extern "C" void kernel_launch(void* const* d_in, const int* in_sizes, int n_in,
                              void* d_out, int out_size, void* d_ws, size_t ws_size,
                              hipStream_t stream) {
  const float* embed_w = (const float*)d_in[0];
  const float* w_ih = (const float*)d_in[1];
  const float* w_hh = (const float*)d_in[2];
  const float* b_ih = (const float*)d_in[3];
  const float* b_hh = (const float*)d_in[4];
  const float* wz1 = (const float*)d_in[5];
  const float* bz1 = (const float*)d_in[6];
  const float* wz2 = (const float*)d_in[7];
  const float* bz2 = (const float*)d_in[8];
  const float* wb1 = (const float*)d_in[9];
  const float* bb1 = (const float*)d_in[10];
  const float* wb2 = (const float*)d_in[11];
  const float* bb2 = (const float*)d_in[12];
  const float* wd1 = (const float*)d_in[13];
  const float* bd1 = (const float*)d_in[14];
  const float* wd2 = (const float*)d_in[15];
  const float* bd2 = (const float*)d_in[16];
  const int* inputs = (const int*)d_in[17];
  const int* lengths = (const int*)d_in[18];

  char* ws = (char*)d_ws;
  size_t off = 0;
  auto alloc = [&](size_t n) { char* p = ws + off; off += (n + 255) & ~(size_t)255; return p; };
  unsigned short* wih_b = (unsigned short*)alloc((size_t)1024 * 256 * 2);
  unsigned short* wpk   = (unsigned short*)alloc((size_t)1024 * 256 * 2);
  unsigned short* wb1_b = (unsigned short*)alloc((size_t)256 * 256 * 2);
  float* biasg = (float*)alloc(1024 * 4);
  unsigned int* flags = (unsigned int*)alloc(16 * 4);
  unsigned short* bufA  = (unsigned short*)alloc((size_t)32768 * 256 * 2);
  unsigned short* enc_b = (unsigned short*)alloc((size_t)32768 * 256 * 2);
  float* lb    = (float*)alloc((size_t)32768 * 4);
  float* lca   = (float*)alloc((size_t)32768 * 4);
  float* maskb = (float*)alloc((size_t)32768 * 4);
  float* rout  = (float*)alloc((size_t)256 * 256 * 4);
  float* zbuf  = (float*)alloc((size_t)256 * 64 * 4);
  float* pred  = (float*)alloc((size_t)256 * 512 * 4);
  size_t fixed = off;
  bool xwf32 = (ws_size >= fixed + (size_t)32768 * 1024 * 4);
  void* xw = alloc(xwf32 ? (size_t)32768 * 1024 * 4 : (size_t)32768 * 1024 * 2);

  unsigned kb[4][2], kz[4][2];
  for (int s = 0; s < 4; ++s) {
    tf2x32(0u, 42u, 0u, (unsigned)(2 * s), &kb[s][0], &kb[s][1]);
    tf2x32(0u, 42u, 0u, (unsigned)(2 * s + 1), &kz[s][0], &kz[s][1]);
  }

  float* out = (float*)d_out;
  float* encs = out;
  float* recs = out + 33554432;
  float* masks = out + 100663296;
  float* blog = out + 100761600;
  float* bsamp = out + 100859904;
  float* zlog = out + 100990976;
  float* zsamp = out + 101122048;

  prep_k<<<256, 256, 0, stream>>>(w_ih, w_hh, wb1, b_ih, b_hh, wih_b, wpk, wb1_b,
                                  biasg, flags);
  embed_k<<<32768, 256, 0, stream>>>(inputs, embed_w, bufA);
  {
    dim3 g(32768 / 128, 1024 / 128);
    gemm_bf16<<<g, 256, 0, stream>>>(bufA, wih_b, biasg,
                                     xwf32 ? (float*)xw : nullptr,
                                     xwf32 ? nullptr : (unsigned short*)xw,
                                     32768, 1024, 256, 0);
  }

  for (int seg = 0; seg < 4; ++seg) {
    unsigned fb = (unsigned)seg * 2048u;  // 16 waves/rg * 128 steps per segment
    if (xwf32)
      lstm_reg<true><<<64, 256, 0, stream>>>(wpk, xw, maskb, seg > 0 ? 1 : 0,
                                             encs + (size_t)seg * 8388608, enc_b,
                                             flags, fb);
    else
      lstm_reg<false><<<64, 256, 0, stream>>>(wpk, xw, maskb, seg > 0 ? 1 : 0,
                                              encs + (size_t)seg * 8388608, enc_b,
                                              flags, fb);

    if (seg < 3) {
      dim3 g(32768 / 128, 256 / 128);
      gemm_bf16<<<g, 256, 0, stream>>>(enc_b, wb1_b, bb1, nullptr, bufA,
                                       32768, 256, 256, 1);
      gemv_lb<<<4096, 512, 0, stream>>>(bufA, wb2, bb2, lb);
      boundary_k<<<256, 128, 0, stream>>>(lb, seg, kb[seg][0], kb[seg][1],
                                          blog + (size_t)seg * 32768,
                                          bsamp + (size_t)seg * 32768,
                                          masks + (size_t)seg * 32768, lca, maskb);
    } else {
      onehot_k<<<256, 128, 0, stream>>>(lengths, bsamp + (size_t)3 * 32768);
    }
    readout_k<<<256, 256, 0, stream>>>(encs + (size_t)seg * 8388608,
                                       bsamp + (size_t)seg * 32768, rout);
    zhead_k<<<256, 128, 0, stream>>>(rout, wz1, bz1, wz2, bz2, kz[seg][0], kz[seg][1],
                                     zlog + (size_t)seg * 32768,
                                     zsamp + (size_t)seg * 16384, zbuf);
    decode_k<<<256, 256, 0, stream>>>(zbuf, wd1, bd1, wd2, bd2, pred);
    bcast_k<<<32768, 128, 0, stream>>>(pred, recs + (size_t)seg * 16777216);
  }
}

// Round 3
// 5033.316 us; speedup vs baseline: 2.0424x; 2.0424x over previous
//
#include <hip/hip_runtime.h>
#include <hip/hip_bf16.h>

// ============================================================================
// CompILE forward: B=256, T=128, V=512, H=256, L=64, S=4
// Round 3: LSTM = 64-block cooperative, W_hh pinned in registers (asm pin),
// h exchanged via write-through agent-scope atomic stores + vmcnt(0) + flag
// atomics. NO __threadfence (no L2 writeback/invalidate in the loop).
// ============================================================================
#define RNG_VARIANT 2

typedef __attribute__((ext_vector_type(8))) short bf16x8;
typedef __attribute__((ext_vector_type(4))) float f32x4;

// ---------------------------------------------------------------- helpers ---
__host__ __device__ inline void tf2x32(unsigned k0, unsigned k1,
                                       unsigned x0, unsigned x1,
                                       unsigned* r0, unsigned* r1) {
  unsigned ks2 = k0 ^ k1 ^ 0x1BD11BDAu;
#define TFR(r) { x0 += x1; x1 = (x1 << r) | (x1 >> (32 - r)); x1 ^= x0; }
  x0 += k0; x1 += k1;
  TFR(13) TFR(15) TFR(26) TFR(6)  x0 += k1;  x1 += ks2 + 1u;
  TFR(17) TFR(29) TFR(16) TFR(24) x0 += ks2; x1 += k0 + 2u;
  TFR(13) TFR(15) TFR(26) TFR(6)  x0 += k0;  x1 += k1 + 3u;
  TFR(17) TFR(29) TFR(16) TFR(24) x0 += k1;  x1 += ks2 + 4u;
  TFR(13) TFR(15) TFR(26) TFR(6)  x0 += ks2; x1 += k0 + 5u;
#undef TFR
  *r0 = x0; *r1 = x1;
}

__device__ __forceinline__ unsigned rng_bits32(unsigned k0, unsigned k1,
                                               unsigned n, unsigned half) {
#if RNG_VARIANT == 2
  unsigned o0, o1; tf2x32(k0, k1, 0u, n, &o0, &o1); return o0 ^ o1;
#elif RNG_VARIANT == 1
  unsigned o0, o1; tf2x32(k0, k1, 0u, n, &o0, &o1); return o1;
#else
  unsigned i0 = (n < half) ? n : n - half;
  unsigned o0, o1; tf2x32(k0, k1, i0, i0 + half, &o0, &o1);
  return (n < half) ? o0 : o1;
#endif
}

__device__ __forceinline__ float bits_to_unit(unsigned bits) {
  return __uint_as_float((bits >> 9) | 0x3f800000u) - 1.0f;
}

__device__ __forceinline__ unsigned short f2bf(float x) {
  union { float f; unsigned u; } v; v.f = x;
  unsigned r = v.u + 0x7fffu + ((v.u >> 16) & 1u);  // RNE
  return (unsigned short)(r >> 16);
}
__device__ __forceinline__ float bf2f(unsigned short h) {
  return __uint_as_float(((unsigned)h) << 16);
}

__device__ __forceinline__ float sigm(float x) {
  return 1.0f / (1.0f + __expf(-x));
}
__device__ __forceinline__ float tanh_f(float x) {
  float ax = fabsf(x);
  float e = __expf(-2.0f * ax);
  float t = (1.0f - e) / (1.0f + e);
  return copysignf(t, x);
}

// XLA ErfInv32 (Giles), w = -log1p(-x*x)
__device__ __forceinline__ float erfinv_f(float x) {
  float w = -log1pf(-x * x);
  float p;
  if (w < 5.0f) {
    w -= 2.5f;
    p = 2.81022636e-08f;
    p = fmaf(p, w, 3.43273939e-07f);
    p = fmaf(p, w, -3.5233877e-06f);
    p = fmaf(p, w, -4.39150654e-06f);
    p = fmaf(p, w, 0.00021858087f);
    p = fmaf(p, w, -0.00125372503f);
    p = fmaf(p, w, -0.00417768164f);
    p = fmaf(p, w, 0.246640727f);
    p = fmaf(p, w, 1.50140941f);
  } else {
    w = sqrtf(w) - 3.0f;
    p = -0.000200214257f;
    p = fmaf(p, w, 0.000100950558f);
    p = fmaf(p, w, 0.00134934322f);
    p = fmaf(p, w, -0.00367342844f);
    p = fmaf(p, w, 0.00573950773f);
    p = fmaf(p, w, -0.0076224613f);
    p = fmaf(p, w, 0.00943887047f);
    p = fmaf(p, w, 1.00167406f);
    p = fmaf(p, w, 2.83297682f);
  }
  return p * x;
}

// ------------------------------------------------------------- prep/embed ---
__global__ void prep_k(const float* __restrict__ w_ih, const float* __restrict__ w_hh,
                       const float* __restrict__ wb1, const float* __restrict__ b_ih,
                       const float* __restrict__ b_hh,
                       unsigned short* __restrict__ wih_b, unsigned short* __restrict__ wpk,
                       unsigned short* __restrict__ wb1_b, float* __restrict__ biasg,
                       unsigned int* __restrict__ flags) {
  int i = blockIdx.x * 256 + threadIdx.x;            // 65536 threads
  for (int idx = i; idx < 262144; idx += 65536) wih_b[idx] = f2bf(w_ih[idx]);
  if (i < 65536) wb1_b[i] = f2bf(wb1[i]);
  if (i < 1024) biasg[i] = b_ih[i] + b_hh[i];
  if (i < 16) flags[i] = 0u;
  if (i < 32768) {
    int l = i & 63, ks = (i >> 6) & 7, tile = i >> 9;
    int n = tile * 16 + (l & 15);
    int kb = ks * 32 + (l >> 4) * 8;
    const float* src = w_hh + (size_t)n * 256 + kb;
#pragma unroll
    for (int j = 0; j < 8; ++j) wpk[(size_t)i * 8 + j] = f2bf(src[j]);
  }
}

__global__ void embed_k(const int* __restrict__ inputs, const float* __restrict__ embw,
                        unsigned short* __restrict__ emb) {
  int bt = blockIdx.x, h = threadIdx.x;
  emb[(size_t)bt * 256 + h] = f2bf(embw[(size_t)inputs[bt] * 256 + h]);
}

// ------------------------------------------------------------------- GEMM ---
__global__ __launch_bounds__(256) void gemm_bf16(
    const unsigned short* __restrict__ A, const unsigned short* __restrict__ Bt,
    const float* __restrict__ bias, float* __restrict__ outF,
    unsigned short* __restrict__ outB, int M, int N, int K, int relu) {
  __shared__ __align__(16) unsigned short As[128][40];
  __shared__ __align__(16) unsigned short Bs[128][40];
  int tid = threadIdx.x;
  int m0 = blockIdx.x * 128, n0 = blockIdx.y * 128;
  int w = tid >> 6, l = tid & 63;
  int wr = w >> 1, wc = w & 1;
  int lr = l & 15, lq = l >> 4;
  f32x4 acc[4][4];
#pragma unroll
  for (int i = 0; i < 4; ++i)
#pragma unroll
    for (int j = 0; j < 4; ++j) acc[i][j] = (f32x4)(0.0f);
  int sr = tid >> 2, sk = (tid & 3) * 8;
#pragma unroll 1
  for (int kc = 0; kc < K; kc += 32) {
#pragma unroll
    for (int p = 0; p < 2; ++p) {
      int row = sr + p * 64;
      *(bf16x8*)&As[row][sk] = *(const bf16x8*)(A + (size_t)(m0 + row) * K + kc + sk);
      *(bf16x8*)&Bs[row][sk] = *(const bf16x8*)(Bt + (size_t)(n0 + row) * K + kc + sk);
    }
    __syncthreads();
    bf16x8 af[4], bfr[4];
#pragma unroll
    for (int i = 0; i < 4; ++i) {
      af[i] = *(const bf16x8*)&As[wr * 64 + i * 16 + lr][lq * 8];
      bfr[i] = *(const bf16x8*)&Bs[wc * 64 + i * 16 + lr][lq * 8];
    }
#pragma unroll
    for (int i = 0; i < 4; ++i)
#pragma unroll
      for (int j = 0; j < 4; ++j)
        acc[i][j] = __builtin_amdgcn_mfma_f32_16x16x32_bf16(af[i], bfr[j], acc[i][j], 0, 0, 0);
    __syncthreads();
  }
#pragma unroll
  for (int i = 0; i < 4; ++i)
#pragma unroll
    for (int j = 0; j < 4; ++j) {
      int col = n0 + wc * 64 + j * 16 + lr;
      float bv = bias ? bias[col] : 0.0f;
#pragma unroll
      for (int q = 0; q < 4; ++q) {
        int row = m0 + wr * 64 + i * 16 + lq * 4 + q;
        float v = acc[i][j][q] + bv;
        if (relu) v = fmaxf(v, 0.0f);
        size_t o = (size_t)row * N + col;
        if (outF) outF[o] = v;
        if (outB) outB[o] = f2bf(v);
      }
    }
}

// ------------------------------------------------------------------- LSTM ---
// 64 blocks = 16 row-groups x 4 col-blocks, 256 threads (4 waves).
// Swapped MFMA: D[row = gate-col, col = batch] = mfma(W_frag, h_frag).
// Thread covers 4 CONSECUTIVE h-cols (nsub..nsub+3) of ONE batch row.
// W slice pinned in registers via asm; h exchanged as 8B write-through
// agent-scope atomic stores; release = s_waitcnt vmcnt(0) + flag atomicAdd.
template <bool XWF32>
__global__ __launch_bounds__(256, 1) void lstm_reg(
    const unsigned short* __restrict__ Wpk, const void* __restrict__ xw_,
    const float* __restrict__ mask_buf, int use_mask,
    float* __restrict__ enc_out, unsigned short* __restrict__ enc_b,
    unsigned int* flags, unsigned int flag_base) {
  const int tid = threadIdx.x;
  const int w = tid >> 6, l = tid & 63;
  const int lr = l & 15, lq = l >> 4;
  const int rg = blockIdx.x >> 2, cb = blockIdx.x & 3;
  const int batch = rg * 16 + lr;              // batch row this thread covers
  const int nsub = cb * 64 + w * 16 + lq * 4;  // h-col base (4 consecutive)

  // ---- W tiles -> registers: gate g uses packed tile (g*16 + cb*4 + w) ----
  bf16x8 Wr[4][8];
#pragma unroll
  for (int g = 0; g < 4; ++g) {
    const unsigned short* bp = Wpk + (size_t)(g * 16 + cb * 4 + w) * 4096;
#pragma unroll
    for (int ks = 0; ks < 8; ++ks)
      Wr[g][ks] = *(const bf16x8*)(bp + ks * 512 + l * 8);
  }
  // pin: asm result cannot be rematerialized -> stays register-resident
#pragma unroll
  for (int g = 0; g < 4; ++g)
#pragma unroll
    for (int ks = 0; ks < 8; ++ks)
      asm volatile("" : "+v"(Wr[g][ks]));

  float cst[4] = {0.f, 0.f, 0.f, 0.f};
  unsigned int* flag = flags + rg;

  const float* xwf = (const float*)xw_;
  const unsigned short* xwb = (const unsigned short*)xw_;
  f32x4 xwf4[4];
  uint2 xwu2[4];
  float mvp;

#define PREFETCH(T)                                                          \
  {                                                                          \
    size_t base_ = ((size_t)batch * 128 + (T)) * 1024 + nsub;                \
    _Pragma("unroll") for (int g = 0; g < 4; ++g) {                          \
      if (XWF32)                                                             \
        xwf4[g] = *(const f32x4*)(xwf + base_ + g * 256);                    \
      else                                                                   \
        xwu2[g] = *(const uint2*)(xwb + base_ + g * 256);                    \
    }                                                                        \
    mvp = use_mask ? mask_buf[batch * 128 + (T)] : 1.0f;                     \
  }

  PREFETCH(0);

#pragma unroll 1
  for (int t = 0; t < 128; ++t) {
    f32x4 acc[4];
#pragma unroll
    for (int g = 0; g < 4; ++g) {
      if (XWF32) {
        acc[g] = xwf4[g];
      } else {
        acc[g][0] = __uint_as_float(xwu2[g].x << 16);
        acc[g][1] = __uint_as_float(xwu2[g].x & 0xffff0000u);
        acc[g][2] = __uint_as_float(xwu2[g].y << 16);
        acc[g][3] = __uint_as_float(xwu2[g].y & 0xffff0000u);
      }
    }
    float mv = mvp;

    if (t < 127) PREFETCH(t + 1);  // issue next-step loads before the spin

    if (t > 0) {
      unsigned thr = flag_base + 16u * (unsigned)t;
      while (__hip_atomic_load(flag, __ATOMIC_RELAXED, __HIP_MEMORY_SCOPE_AGENT) < thr)
        __builtin_amdgcn_s_sleep(1);
      const unsigned short* hrow = enc_b + ((size_t)batch * 128 + (t - 1)) * 256;
      bf16x8 af[8];
#pragma unroll
      for (int ks = 0; ks < 8; ++ks)
        af[ks] = *(const bf16x8*)(hrow + ks * 32 + lq * 8);
#pragma unroll
      for (int ks = 0; ks < 8; ++ks)
#pragma unroll
        for (int g = 0; g < 4; ++g)
          acc[g] = __builtin_amdgcn_mfma_f32_16x16x32_bf16(Wr[g][ks], af[ks],
                                                           acc[g], 0, 0, 0);
    }

    // activations: thread owns (batch, h-cols nsub..nsub+3)
    float hv[4];
#pragma unroll
    for (int q = 0; q < 4; ++q) {
      float ig = acc[0][q], fg = acc[1][q], gg = acc[2][q], og = acc[3][q];
      float cn = sigm(fg) * cst[q] + sigm(ig) * tanh_f(gg);
      float hq = sigm(og) * tanh_f(cn);
      hq *= mv;
      cn *= mv;
      cst[q] = cn;
      hv[q] = hq;
    }
    size_t eo = ((size_t)batch * 128 + t) * 256 + nsub;
    f32x4 hvv;
    hvv[0] = hv[0]; hvv[1] = hv[1]; hvv[2] = hv[2]; hvv[3] = hv[3];
    *(f32x4*)(enc_out + eo) = hvv;  // plain f32 store (read after kernel end)
    unsigned long long pk =
        (unsigned long long)f2bf(hv[0]) |
        ((unsigned long long)f2bf(hv[1]) << 16) |
        ((unsigned long long)f2bf(hv[2]) << 32) |
        ((unsigned long long)f2bf(hv[3]) << 48);
    __hip_atomic_store((unsigned long long*)(enc_b + eo), pk,
                       __ATOMIC_RELAXED, __HIP_MEMORY_SCOPE_AGENT);

    asm volatile("s_waitcnt vmcnt(0)" ::: "memory");  // release: stores at LLC
    if (l == 0)
      __hip_atomic_fetch_add(flag, 1u, __ATOMIC_RELAXED, __HIP_MEMORY_SCOPE_AGENT);
  }
#undef PREFETCH
}

// ------------------------------------------------------------------- GEMV ---
__global__ __launch_bounds__(512) void gemv_lb(const unsigned short* __restrict__ hid,
                                               const float* __restrict__ wb2,
                                               const float* __restrict__ bb2,
                                               float* __restrict__ lb) {
  int l = threadIdx.x & 63, w = threadIdx.x >> 6;
  int row = blockIdx.x * 8 + w;
  const unsigned short* hp = hid + (size_t)row * 256 + l * 4;
  uint2 hv = *(const uint2*)hp;
  float4 wv = *(const float4*)(wb2 + l * 4);
  float s = bf2f((unsigned short)(hv.x & 0xffff)) * wv.x +
            bf2f((unsigned short)(hv.x >> 16)) * wv.y +
            bf2f((unsigned short)(hv.y & 0xffff)) * wv.z +
            bf2f((unsigned short)(hv.y >> 16)) * wv.w;
#pragma unroll
  for (int d = 32; d > 0; d >>= 1) s += __shfl_xor(s, d);
  if (l == 0) lb[row] = s + bb2[0];
}

// --------------------------------------------------------------- boundary ---
__global__ __launch_bounds__(128) void boundary_k(
    const float* __restrict__ lb, int seg, unsigned k0, unsigned k1,
    float* __restrict__ blog, float* __restrict__ bsamp, float* __restrict__ masks_o,
    float* __restrict__ lca, float* __restrict__ maskb) {
  int b = blockIdx.x, t = threadIdx.x;
  int l = t & 63, w = t >> 6;
  float v = lb[b * 128 + t];
  if (t == 0) v = -1e30f;
  unsigned bits = rng_bits32(k0, k1, (unsigned)(b * 128 + t), 16384u);
  float u = bits_to_unit(bits);
  float g = -logf(1e-17f - logf(u + 1e-17f));
  float y = v + g;  // TEMP_B = 1
  float m = y;
#pragma unroll
  for (int d = 32; d > 0; d >>= 1) m = fmaxf(m, __shfl_xor(m, d));
  __shared__ float xs[2];
  if (l == 0) xs[w] = m;
  __syncthreads();
  m = fmaxf(xs[0], xs[1]);
  float e = expf(y - m);
  float ssum = e;
#pragma unroll
  for (int d = 32; d > 0; d >>= 1) ssum += __shfl_xor(ssum, d);
  __shared__ float ss2[2];
  if (l == 0) ss2[w] = ssum;
  __syncthreads();
  ssum = ss2[0] + ss2[1];
  float sb = e / ssum;
  blog[b * 128 + t] = v;
  bsamp[b * 128 + t] = sb;
  float cs = sb;
#pragma unroll
  for (int d = 1; d < 64; d <<= 1) {
    float p = __shfl_up(cs, d);
    if (l >= d) cs += p;
  }
  __shared__ float wt[2];
  if (l == 63) wt[w] = cs;
  __syncthreads();
  if (w == 1) cs += wt[0];
  float lg = logf(cs + 1e-17f);
  float a = (seg == 0 ? 0.0f : lca[b * 128 + t]) + lg;
  lca[b * 128 + t] = a;
  float mk = expf(a);
  maskb[b * 128 + t] = mk;
  masks_o[b * 128 + t] = mk;
}

__global__ __launch_bounds__(128) void onehot_k(const int* __restrict__ lengths,
                                                float* __restrict__ bsamp) {
  int b = blockIdx.x, t = threadIdx.x;
  bsamp[b * 128 + t] = (t == lengths[b] - 1) ? 1.0f : 0.0f;
}

// ---------------------------------------------------------------- readout ---
__global__ __launch_bounds__(256) void readout_k(const float* __restrict__ enc,
                                                 const float* __restrict__ sb,
                                                 float* __restrict__ rout) {
  int b = blockIdx.x, h = threadIdx.x;
  __shared__ float sl[128];
  if (h < 128) sl[h] = sb[b * 128 + h];
  __syncthreads();
  float a = 0.0f;
  const float* ep = enc + (size_t)b * 128 * 256 + h;
#pragma unroll 4
  for (int t2 = 0; t2 < 127; ++t2) a += ep[(size_t)t2 * 256] * sl[t2 + 1];
  rout[b * 256 + h] = a;
}

// ----------------------------------------------------------------- z head ---
__global__ __launch_bounds__(128) void zhead_k(
    const float* __restrict__ rout, const float* __restrict__ wz1,
    const float* __restrict__ bz1, const float* __restrict__ wz2,
    const float* __restrict__ bz2, unsigned k0, unsigned k1,
    float* __restrict__ zlo, float* __restrict__ zsa, float* __restrict__ zbuf) {
  int b = blockIdx.x, t = threadIdx.x;
  __shared__ float rl[256], hz[256], lzs[128];
  rl[t] = rout[b * 256 + t];
  rl[t + 128] = rout[b * 256 + t + 128];
  __syncthreads();
  for (int h = t; h < 256; h += 128) {
    float a = bz1[h];
    const float* wp = wz1 + (size_t)h * 256;
    for (int k2 = 0; k2 < 256; ++k2) a += rl[k2] * wp[k2];
    hz[h] = fmaxf(a, 0.0f);
  }
  __syncthreads();
  {
    float a = bz2[t];
    const float* wp = wz2 + (size_t)t * 256;
    for (int k2 = 0; k2 < 256; ++k2) a += hz[k2] * wp[k2];
    zlo[b * 128 + t] = a;
    lzs[t] = a;
  }
  __syncthreads();
  if (t < 64) {
    unsigned bits = rng_bits32(k0, k1, (unsigned)(b * 64 + t), 8192u);
    float f = bits_to_unit(bits);
    const float LO = -0x1.fffffep-1f;
    float u = fmaxf(LO, f * 2.0f + LO);
    float ez = 1.4142135623730951f * erfinv_f(u);
    float z = lzs[t] + expf(0.5f * lzs[t + 64]) * ez;
    zsa[b * 64 + t] = z;
    zbuf[b * 64 + t] = z;
  }
}

// ----------------------------------------------------------------- decode ---
__global__ __launch_bounds__(256) void decode_k(
    const float* __restrict__ zbuf, const float* __restrict__ wd1,
    const float* __restrict__ bd1, const float* __restrict__ wd2,
    const float* __restrict__ bd2, float* __restrict__ pred) {
  int b = blockIdx.x, t = threadIdx.x;
  __shared__ float zl[64], hd[256];
  if (t < 64) zl[t] = zbuf[b * 64 + t];
  __syncthreads();
  {
    float a = bd1[t];
    const float* wp = wd1 + (size_t)t * 64;
    for (int k2 = 0; k2 < 64; ++k2) a += zl[k2] * wp[k2];
    hd[t] = fmaxf(a, 0.0f);
  }
  __syncthreads();
  for (int v2 = t; v2 < 512; v2 += 256) {
    float p = bd2[v2];
    const float* wp = wd2 + (size_t)v2 * 256;
    for (int k2 = 0; k2 < 256; ++k2) p += hd[k2] * wp[k2];
    pred[b * 512 + v2] = p;
  }
}

__global__ __launch_bounds__(128) void bcast_k(const float* __restrict__ pred,
                                               float* __restrict__ recs) {
  int bt = blockIdx.x;
  int b = bt >> 7;
  float4 v = ((const float4*)(pred + (size_t)b * 512))[threadIdx.x];
  ((float4*)(recs + (size_t)bt * 512))[threadIdx.x] = v;
}

// ------------------------------------------------------------------- host ---
extern "C" void kernel_launch(void* const* d_in, const int* in_sizes, int n_in,
                              void* d_out, int out_size, void* d_ws, size_t ws_size,
                              hipStream_t stream) {
  const float* embed_w = (const float*)d_in[0];
  const float* w_ih = (const float*)d_in[1];
  const float* w_hh = (const float*)d_in[2];
  const float* b_ih = (const float*)d_in[3];
  const float* b_hh = (const float*)d_in[4];
  const float* wz1 = (const float*)d_in[5];
  const float* bz1 = (const float*)d_in[6];
  const float* wz2 = (const float*)d_in[7];
  const float* bz2 = (const float*)d_in[8];
  const float* wb1 = (const float*)d_in[9];
  const float* bb1 = (const float*)d_in[10];
  const float* wb2 = (const float*)d_in[11];
  const float* bb2 = (const float*)d_in[12];
  const float* wd1 = (const float*)d_in[13];
  const float* bd1 = (const float*)d_in[14];
  const float* wd2 = (const float*)d_in[15];
  const float* bd2 = (const float*)d_in[16];
  const int* inputs = (const int*)d_in[17];
  const int* lengths = (const int*)d_in[18];

  char* ws = (char*)d_ws;
  size_t off = 0;
  auto alloc = [&](size_t n) { char* p = ws + off; off += (n + 255) & ~(size_t)255; return p; };
  unsigned short* wih_b = (unsigned short*)alloc((size_t)1024 * 256 * 2);
  unsigned short* wpk   = (unsigned short*)alloc((size_t)1024 * 256 * 2);
  unsigned short* wb1_b = (unsigned short*)alloc((size_t)256 * 256 * 2);
  float* biasg = (float*)alloc(1024 * 4);
  unsigned int* flags = (unsigned int*)alloc(16 * 4);
  unsigned short* bufA  = (unsigned short*)alloc((size_t)32768 * 256 * 2);
  unsigned short* enc_b = (unsigned short*)alloc((size_t)32768 * 256 * 2);
  float* lb    = (float*)alloc((size_t)32768 * 4);
  float* lca   = (float*)alloc((size_t)32768 * 4);
  float* maskb = (float*)alloc((size_t)32768 * 4);
  float* rout  = (float*)alloc((size_t)256 * 256 * 4);
  float* zbuf  = (float*)alloc((size_t)256 * 64 * 4);
  float* pred  = (float*)alloc((size_t)256 * 512 * 4);
  size_t fixed = off;
  bool xwf32 = (ws_size >= fixed + (size_t)32768 * 1024 * 4);
  void* xw = alloc(xwf32 ? (size_t)32768 * 1024 * 4 : (size_t)32768 * 1024 * 2);

  unsigned kb[4][2], kz[4][2];
  for (int s = 0; s < 4; ++s) {
    tf2x32(0u, 42u, 0u, (unsigned)(2 * s), &kb[s][0], &kb[s][1]);
    tf2x32(0u, 42u, 0u, (unsigned)(2 * s + 1), &kz[s][0], &kz[s][1]);
  }

  float* out = (float*)d_out;
  float* encs = out;
  float* recs = out + 33554432;
  float* masks = out + 100663296;
  float* blog = out + 100761600;
  float* bsamp = out + 100859904;
  float* zlog = out + 100990976;
  float* zsamp = out + 101122048;

  prep_k<<<256, 256, 0, stream>>>(w_ih, w_hh, wb1, b_ih, b_hh, wih_b, wpk, wb1_b,
                                  biasg, flags);
  embed_k<<<32768, 256, 0, stream>>>(inputs, embed_w, bufA);
  {
    dim3 g(32768 / 128, 1024 / 128);
    gemm_bf16<<<g, 256, 0, stream>>>(bufA, wih_b, biasg,
                                     xwf32 ? (float*)xw : nullptr,
                                     xwf32 ? nullptr : (unsigned short*)xw,
                                     32768, 1024, 256, 0);
  }

  for (int seg = 0; seg < 4; ++seg) {
    unsigned fb = (unsigned)seg * 2048u;  // 16 wave-increments/rg/step * 128
    if (xwf32)
      lstm_reg<true><<<64, 256, 0, stream>>>(wpk, xw, maskb, seg > 0 ? 1 : 0,
                                             encs + (size_t)seg * 8388608, enc_b,
                                             flags, fb);
    else
      lstm_reg<false><<<64, 256, 0, stream>>>(wpk, xw, maskb, seg > 0 ? 1 : 0,
                                              encs + (size_t)seg * 8388608, enc_b,
                                              flags, fb);

    if (seg < 3) {
      dim3 g(32768 / 128, 256 / 128);
      gemm_bf16<<<g, 256, 0, stream>>>(enc_b, wb1_b, bb1, nullptr, bufA,
                                       32768, 256, 256, 1);
      gemv_lb<<<4096, 512, 0, stream>>>(bufA, wb2, bb2, lb);
      boundary_k<<<256, 128, 0, stream>>>(lb, seg, kb[seg][0], kb[seg][1],
                                          blog + (size_t)seg * 32768,
                                          bsamp + (size_t)seg * 32768,
                                          masks + (size_t)seg * 32768, lca, maskb);
    } else {
      onehot_k<<<256, 128, 0, stream>>>(lengths, bsamp + (size_t)3 * 32768);
    }
    readout_k<<<256, 256, 0, stream>>>(encs + (size_t)seg * 8388608,
                                       bsamp + (size_t)seg * 32768, rout);
    zhead_k<<<256, 128, 0, stream>>>(rout, wz1, bz1, wz2, bz2, kz[seg][0], kz[seg][1],
                                     zlog + (size_t)seg * 32768,
                                     zsamp + (size_t)seg * 16384, zbuf);
    decode_k<<<256, 256, 0, stream>>>(zbuf, wd1, bd1, wd2, bd2, pred);
    bcast_k<<<32768, 128, 0, stream>>>(pred, recs + (size_t)seg * 16777216);
  }
}

// Round 4
// 2105.119 us; speedup vs baseline: 4.8834x; 2.3910x over previous
//
#include <hip/hip_runtime.h>
#include <hip/hip_bf16.h>

// ============================================================================
// CompILE forward: B=256, T=128, V=512, H=256, L=64, S=4
// Round 4: LSTM = 64-block cooperative; W slice resident in LDS (128 KB,
// ds_read per step, issued+pinned BEFORE the spin so latency hides under it);
// h exchanged via write-through agent-scope atomic stores; release =
// vmcnt(0) + __syncthreads + ONE flag atomicAdd per block (threshold 4t).
// ============================================================================
#define RNG_VARIANT 2

typedef __attribute__((ext_vector_type(8))) short bf16x8;
typedef __attribute__((ext_vector_type(4))) float f32x4;

// ---------------------------------------------------------------- helpers ---
__host__ __device__ inline void tf2x32(unsigned k0, unsigned k1,
                                       unsigned x0, unsigned x1,
                                       unsigned* r0, unsigned* r1) {
  unsigned ks2 = k0 ^ k1 ^ 0x1BD11BDAu;
#define TFR(r) { x0 += x1; x1 = (x1 << r) | (x1 >> (32 - r)); x1 ^= x0; }
  x0 += k0; x1 += k1;
  TFR(13) TFR(15) TFR(26) TFR(6)  x0 += k1;  x1 += ks2 + 1u;
  TFR(17) TFR(29) TFR(16) TFR(24) x0 += ks2; x1 += k0 + 2u;
  TFR(13) TFR(15) TFR(26) TFR(6)  x0 += k0;  x1 += k1 + 3u;
  TFR(17) TFR(29) TFR(16) TFR(24) x0 += k1;  x1 += ks2 + 4u;
  TFR(13) TFR(15) TFR(26) TFR(6)  x0 += ks2; x1 += k0 + 5u;
#undef TFR
  *r0 = x0; *r1 = x1;
}

__device__ __forceinline__ unsigned rng_bits32(unsigned k0, unsigned k1,
                                               unsigned n, unsigned half) {
#if RNG_VARIANT == 2
  unsigned o0, o1; tf2x32(k0, k1, 0u, n, &o0, &o1); return o0 ^ o1;
#elif RNG_VARIANT == 1
  unsigned o0, o1; tf2x32(k0, k1, 0u, n, &o0, &o1); return o1;
#else
  unsigned i0 = (n < half) ? n : n - half;
  unsigned o0, o1; tf2x32(k0, k1, i0, i0 + half, &o0, &o1);
  return (n < half) ? o0 : o1;
#endif
}

__device__ __forceinline__ float bits_to_unit(unsigned bits) {
  return __uint_as_float((bits >> 9) | 0x3f800000u) - 1.0f;
}

__device__ __forceinline__ unsigned short f2bf(float x) {
  union { float f; unsigned u; } v; v.f = x;
  unsigned r = v.u + 0x7fffu + ((v.u >> 16) & 1u);  // RNE
  return (unsigned short)(r >> 16);
}
__device__ __forceinline__ float bf2f(unsigned short h) {
  return __uint_as_float(((unsigned)h) << 16);
}

__device__ __forceinline__ float sigm(float x) {
  return 1.0f / (1.0f + __expf(-x));
}
__device__ __forceinline__ float tanh_f(float x) {
  float ax = fabsf(x);
  float e = __expf(-2.0f * ax);
  float t = (1.0f - e) / (1.0f + e);
  return copysignf(t, x);
}

// XLA ErfInv32 (Giles), w = -log1p(-x*x)
__device__ __forceinline__ float erfinv_f(float x) {
  float w = -log1pf(-x * x);
  float p;
  if (w < 5.0f) {
    w -= 2.5f;
    p = 2.81022636e-08f;
    p = fmaf(p, w, 3.43273939e-07f);
    p = fmaf(p, w, -3.5233877e-06f);
    p = fmaf(p, w, -4.39150654e-06f);
    p = fmaf(p, w, 0.00021858087f);
    p = fmaf(p, w, -0.00125372503f);
    p = fmaf(p, w, -0.00417768164f);
    p = fmaf(p, w, 0.246640727f);
    p = fmaf(p, w, 1.50140941f);
  } else {
    w = sqrtf(w) - 3.0f;
    p = -0.000200214257f;
    p = fmaf(p, w, 0.000100950558f);
    p = fmaf(p, w, 0.00134934322f);
    p = fmaf(p, w, -0.00367342844f);
    p = fmaf(p, w, 0.00573950773f);
    p = fmaf(p, w, -0.0076224613f);
    p = fmaf(p, w, 0.00943887047f);
    p = fmaf(p, w, 1.00167406f);
    p = fmaf(p, w, 2.83297682f);
  }
  return p * x;
}

// ------------------------------------------------------------- prep/embed ---
__global__ void prep_k(const float* __restrict__ w_ih, const float* __restrict__ w_hh,
                       const float* __restrict__ wb1, const float* __restrict__ b_ih,
                       const float* __restrict__ b_hh,
                       unsigned short* __restrict__ wih_b, unsigned short* __restrict__ wpk,
                       unsigned short* __restrict__ wb1_b, float* __restrict__ biasg,
                       unsigned int* __restrict__ flags) {
  int i = blockIdx.x * 256 + threadIdx.x;            // 65536 threads
  for (int idx = i; idx < 262144; idx += 65536) wih_b[idx] = f2bf(w_ih[idx]);
  if (i < 65536) wb1_b[i] = f2bf(wb1[i]);
  if (i < 1024) biasg[i] = b_ih[i] + b_hh[i];
  if (i >= 1024 && i < 2048) flags[i - 1024] = 0u;   // 16 flags padded to 64 ints
  if (i < 32768) {
    int l = i & 63, ks = (i >> 6) & 7, tile = i >> 9;
    int n = tile * 16 + (l & 15);
    int kb = ks * 32 + (l >> 4) * 8;
    const float* src = w_hh + (size_t)n * 256 + kb;
#pragma unroll
    for (int j = 0; j < 8; ++j) wpk[(size_t)i * 8 + j] = f2bf(src[j]);
  }
}

__global__ void embed_k(const int* __restrict__ inputs, const float* __restrict__ embw,
                        unsigned short* __restrict__ emb) {
  int bt = blockIdx.x, h = threadIdx.x;
  emb[(size_t)bt * 256 + h] = f2bf(embw[(size_t)inputs[bt] * 256 + h]);
}

// ------------------------------------------------------------------- GEMM ---
__global__ __launch_bounds__(256) void gemm_bf16(
    const unsigned short* __restrict__ A, const unsigned short* __restrict__ Bt,
    const float* __restrict__ bias, float* __restrict__ outF,
    unsigned short* __restrict__ outB, int M, int N, int K, int relu) {
  __shared__ __align__(16) unsigned short As[128][40];
  __shared__ __align__(16) unsigned short Bs[128][40];
  int tid = threadIdx.x;
  int m0 = blockIdx.x * 128, n0 = blockIdx.y * 128;
  int w = tid >> 6, l = tid & 63;
  int wr = w >> 1, wc = w & 1;
  int lr = l & 15, lq = l >> 4;
  f32x4 acc[4][4];
#pragma unroll
  for (int i = 0; i < 4; ++i)
#pragma unroll
    for (int j = 0; j < 4; ++j) acc[i][j] = (f32x4)(0.0f);
  int sr = tid >> 2, sk = (tid & 3) * 8;
#pragma unroll 1
  for (int kc = 0; kc < K; kc += 32) {
#pragma unroll
    for (int p = 0; p < 2; ++p) {
      int row = sr + p * 64;
      *(bf16x8*)&As[row][sk] = *(const bf16x8*)(A + (size_t)(m0 + row) * K + kc + sk);
      *(bf16x8*)&Bs[row][sk] = *(const bf16x8*)(Bt + (size_t)(n0 + row) * K + kc + sk);
    }
    __syncthreads();
    bf16x8 af[4], bfr[4];
#pragma unroll
    for (int i = 0; i < 4; ++i) {
      af[i] = *(const bf16x8*)&As[wr * 64 + i * 16 + lr][lq * 8];
      bfr[i] = *(const bf16x8*)&Bs[wc * 64 + i * 16 + lr][lq * 8];
    }
#pragma unroll
    for (int i = 0; i < 4; ++i)
#pragma unroll
      for (int j = 0; j < 4; ++j)
        acc[i][j] = __builtin_amdgcn_mfma_f32_16x16x32_bf16(af[i], bfr[j], acc[i][j], 0, 0, 0);
    __syncthreads();
  }
#pragma unroll
  for (int i = 0; i < 4; ++i)
#pragma unroll
    for (int j = 0; j < 4; ++j) {
      int col = n0 + wc * 64 + j * 16 + lr;
      float bv = bias ? bias[col] : 0.0f;
#pragma unroll
      for (int q = 0; q < 4; ++q) {
        int row = m0 + wr * 64 + i * 16 + lq * 4 + q;
        float v = acc[i][j][q] + bv;
        if (relu) v = fmaxf(v, 0.0f);
        size_t o = (size_t)row * N + col;
        if (outF) outF[o] = v;
        if (outB) outB[o] = f2bf(v);
      }
    }
}

// ------------------------------------------------------------------- LSTM ---
// 64 blocks = 16 row-groups x 4 col-blocks, 256 threads (4 waves), 1 block/CU.
// Block's W slice (16 tiles, 128 KB) resident in LDS; ds_read per step,
// issued + pinned BEFORE the flag spin so LDS latency hides under the wait.
// Swapped MFMA: D[gate-col, batch] = mfma(W_frag, h_frag).
template <bool XWF32>
__global__ __launch_bounds__(256, 1) void lstm_lds(
    const unsigned short* __restrict__ Wpk, const void* __restrict__ xw_,
    const float* __restrict__ mask_buf, int use_mask,
    float* __restrict__ enc_out, unsigned short* __restrict__ enc_b,
    unsigned int* flags, unsigned int flag_base) {
  __shared__ __align__(16) unsigned short Wl[65536];  // 128 KB W slice
  const int tid = threadIdx.x;
  const int w = tid >> 6, l = tid & 63;
  const int lr = l & 15, lq = l >> 4;
  const int rg = blockIdx.x >> 2, cb = blockIdx.x & 3;
  const int batch = rg * 16 + lr;              // batch row this thread covers
  const int nsub = cb * 64 + w * 16 + lq * 4;  // h-col base (4 consecutive)

  // ---- stage W slice to LDS: dst tile (g*4+wv) <- packed tile g*16+cb*4+wv
  {
    const int4* src4 = (const int4*)Wpk;
    int4* dst4 = (int4*)Wl;
#pragma unroll
    for (int it = 0; it < 32; ++it) {
      int d = tid + it * 256;                 // 8192 int4 total
      int tile = d >> 9, within = d & 511;
      int g = tile >> 2, wv = tile & 3;
      dst4[d] = src4[(size_t)(g * 16 + cb * 4 + wv) * 512 + within];
    }
  }
  __syncthreads();

  float cst[4] = {0.f, 0.f, 0.f, 0.f};
  unsigned int* flag = flags + rg * 64;       // 256B-padded flags

  const float* xwf = (const float*)xw_;
  const unsigned short* xwb = (const unsigned short*)xw_;
  f32x4 xwf4[4];
  uint2 xwu2[4];
  float mvp;

#define PREFETCH(T)                                                          \
  {                                                                          \
    size_t base_ = ((size_t)batch * 128 + (T)) * 1024 + nsub;                \
    _Pragma("unroll") for (int g = 0; g < 4; ++g) {                          \
      if (XWF32)                                                             \
        xwf4[g] = *(const f32x4*)(xwf + base_ + g * 256);                    \
      else                                                                   \
        xwu2[g] = *(const uint2*)(xwb + base_ + g * 256);                    \
    }                                                                        \
    mvp = use_mask ? mask_buf[batch * 128 + (T)] : 1.0f;                     \
  }

  PREFETCH(0);

#pragma unroll 1
  for (int t = 0; t < 128; ++t) {
    f32x4 acc[4];
#pragma unroll
    for (int g = 0; g < 4; ++g) {
      if (XWF32) {
        acc[g] = xwf4[g];
      } else {
        acc[g][0] = __uint_as_float(xwu2[g].x << 16);
        acc[g][1] = __uint_as_float(xwu2[g].x & 0xffff0000u);
        acc[g][2] = __uint_as_float(xwu2[g].y << 16);
        acc[g][3] = __uint_as_float(xwu2[g].y & 0xffff0000u);
      }
    }
    float mv = mvp;

    if (t < 127) PREFETCH(t + 1);  // issue next-step xw/mask loads early

    // W fragments from LDS; opaque offset defeats LICM (keeps pressure low),
    // pin forces issue+complete BEFORE the spin (latency absorbed by wait).
    int woff = 0;
    asm volatile("" : "+v"(woff));
    bf16x8 Wf[4][8];
#pragma unroll
    for (int g = 0; g < 4; ++g)
#pragma unroll
      for (int ks = 0; ks < 8; ++ks)
        Wf[g][ks] = *(const bf16x8*)(Wl + woff + ((g * 4 + w) << 12) +
                                     (ks << 9) + (l << 3));
#pragma unroll
    for (int g = 0; g < 4; ++g)
#pragma unroll
      for (int ks = 0; ks < 8; ++ks)
        asm volatile("" : "+v"(Wf[g][ks]));

    if (t > 0) {
      unsigned thr = flag_base + 4u * (unsigned)t;
      while (__hip_atomic_load(flag, __ATOMIC_RELAXED, __HIP_MEMORY_SCOPE_AGENT) < thr)
        __builtin_amdgcn_s_sleep(1);
      const unsigned short* hrow = enc_b + ((size_t)batch * 128 + (t - 1)) * 256;
      bf16x8 af[8];
#pragma unroll
      for (int ks = 0; ks < 8; ++ks)
        af[ks] = *(const bf16x8*)(hrow + ks * 32 + lq * 8);
#pragma unroll
      for (int ks = 0; ks < 8; ++ks)
#pragma unroll
        for (int g = 0; g < 4; ++g)
          acc[g] = __builtin_amdgcn_mfma_f32_16x16x32_bf16(Wf[g][ks], af[ks],
                                                           acc[g], 0, 0, 0);
    }

    // activations: thread owns (batch, h-cols nsub..nsub+3)
    float hv[4];
#pragma unroll
    for (int q = 0; q < 4; ++q) {
      float ig = acc[0][q], fg = acc[1][q], gg = acc[2][q], og = acc[3][q];
      float cn = sigm(fg) * cst[q] + sigm(ig) * tanh_f(gg);
      float hq = sigm(og) * tanh_f(cn);
      hq *= mv;
      cn *= mv;
      cst[q] = cn;
      hv[q] = hq;
    }
    size_t eo = ((size_t)batch * 128 + t) * 256 + nsub;
    f32x4 hvv;
    hvv[0] = hv[0]; hvv[1] = hv[1]; hvv[2] = hv[2]; hvv[3] = hv[3];
    *(f32x4*)(enc_out + eo) = hvv;  // plain f32 store (read after kernel end)
    unsigned long long pk =
        (unsigned long long)f2bf(hv[0]) |
        ((unsigned long long)f2bf(hv[1]) << 16) |
        ((unsigned long long)f2bf(hv[2]) << 32) |
        ((unsigned long long)f2bf(hv[3]) << 48);
    __hip_atomic_store((unsigned long long*)(enc_b + eo), pk,
                       __ATOMIC_RELAXED, __HIP_MEMORY_SCOPE_AGENT);

    asm volatile("s_waitcnt vmcnt(0)" ::: "memory");  // own stores at LLC
    __syncthreads();                                   // all 4 waves done
    if (tid == 0)
      __hip_atomic_fetch_add(flag, 1u, __ATOMIC_RELAXED, __HIP_MEMORY_SCOPE_AGENT);
  }
#undef PREFETCH
}

// ------------------------------------------------------------------- GEMV ---
__global__ __launch_bounds__(512) void gemv_lb(const unsigned short* __restrict__ hid,
                                               const float* __restrict__ wb2,
                                               const float* __restrict__ bb2,
                                               float* __restrict__ lb) {
  int l = threadIdx.x & 63, w = threadIdx.x >> 6;
  int row = blockIdx.x * 8 + w;
  const unsigned short* hp = hid + (size_t)row * 256 + l * 4;
  uint2 hv = *(const uint2*)hp;
  float4 wv = *(const float4*)(wb2 + l * 4);
  float s = bf2f((unsigned short)(hv.x & 0xffff)) * wv.x +
            bf2f((unsigned short)(hv.x >> 16)) * wv.y +
            bf2f((unsigned short)(hv.y & 0xffff)) * wv.z +
            bf2f((unsigned short)(hv.y >> 16)) * wv.w;
#pragma unroll
  for (int d = 32; d > 0; d >>= 1) s += __shfl_xor(s, d);
  if (l == 0) lb[row] = s + bb2[0];
}

// --------------------------------------------------------------- boundary ---
__global__ __launch_bounds__(128) void boundary_k(
    const float* __restrict__ lb, int seg, unsigned k0, unsigned k1,
    float* __restrict__ blog, float* __restrict__ bsamp, float* __restrict__ masks_o,
    float* __restrict__ lca, float* __restrict__ maskb) {
  int b = blockIdx.x, t = threadIdx.x;
  int l = t & 63, w = t >> 6;
  float v = lb[b * 128 + t];
  if (t == 0) v = -1e30f;
  unsigned bits = rng_bits32(k0, k1, (unsigned)(b * 128 + t), 16384u);
  float u = bits_to_unit(bits);
  float g = -logf(1e-17f - logf(u + 1e-17f));
  float y = v + g;  // TEMP_B = 1
  float m = y;
#pragma unroll
  for (int d = 32; d > 0; d >>= 1) m = fmaxf(m, __shfl_xor(m, d));
  __shared__ float xs[2];
  if (l == 0) xs[w] = m;
  __syncthreads();
  m = fmaxf(xs[0], xs[1]);
  float e = expf(y - m);
  float ssum = e;
#pragma unroll
  for (int d = 32; d > 0; d >>= 1) ssum += __shfl_xor(ssum, d);
  __shared__ float ss2[2];
  if (l == 0) ss2[w] = ssum;
  __syncthreads();
  ssum = ss2[0] + ss2[1];
  float sb = e / ssum;
  blog[b * 128 + t] = v;
  bsamp[b * 128 + t] = sb;
  float cs = sb;
#pragma unroll
  for (int d = 1; d < 64; d <<= 1) {
    float p = __shfl_up(cs, d);
    if (l >= d) cs += p;
  }
  __shared__ float wt[2];
  if (l == 63) wt[w] = cs;
  __syncthreads();
  if (w == 1) cs += wt[0];
  float lg = logf(cs + 1e-17f);
  float a = (seg == 0 ? 0.0f : lca[b * 128 + t]) + lg;
  lca[b * 128 + t] = a;
  float mk = expf(a);
  maskb[b * 128 + t] = mk;
  masks_o[b * 128 + t] = mk;
}

__global__ __launch_bounds__(128) void onehot_k(const int* __restrict__ lengths,
                                                float* __restrict__ bsamp) {
  int b = blockIdx.x, t = threadIdx.x;
  bsamp[b * 128 + t] = (t == lengths[b] - 1) ? 1.0f : 0.0f;
}

// ---------------------------------------------------------------- readout ---
__global__ __launch_bounds__(256) void readout_k(const float* __restrict__ enc,
                                                 const float* __restrict__ sb,
                                                 float* __restrict__ rout) {
  int b = blockIdx.x, h = threadIdx.x;
  __shared__ float sl[128];
  if (h < 128) sl[h] = sb[b * 128 + h];
  __syncthreads();
  float a = 0.0f;
  const float* ep = enc + (size_t)b * 128 * 256 + h;
#pragma unroll 4
  for (int t2 = 0; t2 < 127; ++t2) a += ep[(size_t)t2 * 256] * sl[t2 + 1];
  rout[b * 256 + h] = a;
}

// ----------------------------------------------------------------- z head ---
__global__ __launch_bounds__(128) void zhead_k(
    const float* __restrict__ rout, const float* __restrict__ wz1,
    const float* __restrict__ bz1, const float* __restrict__ wz2,
    const float* __restrict__ bz2, unsigned k0, unsigned k1,
    float* __restrict__ zlo, float* __restrict__ zsa, float* __restrict__ zbuf) {
  int b = blockIdx.x, t = threadIdx.x;
  __shared__ float rl[256], hz[256], lzs[128];
  rl[t] = rout[b * 256 + t];
  rl[t + 128] = rout[b * 256 + t + 128];
  __syncthreads();
  for (int h = t; h < 256; h += 128) {
    float a = bz1[h];
    const float* wp = wz1 + (size_t)h * 256;
    for (int k2 = 0; k2 < 256; ++k2) a += rl[k2] * wp[k2];
    hz[h] = fmaxf(a, 0.0f);
  }
  __syncthreads();
  {
    float a = bz2[t];
    const float* wp = wz2 + (size_t)t * 256;
    for (int k2 = 0; k2 < 256; ++k2) a += hz[k2] * wp[k2];
    zlo[b * 128 + t] = a;
    lzs[t] = a;
  }
  __syncthreads();
  if (t < 64) {
    unsigned bits = rng_bits32(k0, k1, (unsigned)(b * 64 + t), 8192u);
    float f = bits_to_unit(bits);
    const float LO = -0x1.fffffep-1f;
    float u = fmaxf(LO, f * 2.0f + LO);
    float ez = 1.4142135623730951f * erfinv_f(u);
    float z = lzs[t] + expf(0.5f * lzs[t + 64]) * ez;
    zsa[b * 64 + t] = z;
    zbuf[b * 64 + t] = z;
  }
}

// ----------------------------------------------------------------- decode ---
__global__ __launch_bounds__(256) void decode_k(
    const float* __restrict__ zbuf, const float* __restrict__ wd1,
    const float* __restrict__ bd1, const float* __restrict__ wd2,
    const float* __restrict__ bd2, float* __restrict__ pred) {
  int b = blockIdx.x, t = threadIdx.x;
  __shared__ float zl[64], hd[256];
  if (t < 64) zl[t] = zbuf[b * 64 + t];
  __syncthreads();
  {
    float a = bd1[t];
    const float* wp = wd1 + (size_t)t * 64;
    for (int k2 = 0; k2 < 64; ++k2) a += zl[k2] * wp[k2];
    hd[t] = fmaxf(a, 0.0f);
  }
  __syncthreads();
  for (int v2 = t; v2 < 512; v2 += 256) {
    float p = bd2[v2];
    const float* wp = wd2 + (size_t)v2 * 256;
    for (int k2 = 0; k2 < 256; ++k2) p += hd[k2] * wp[k2];
    pred[b * 512 + v2] = p;
  }
}

__global__ __launch_bounds__(128) void bcast_k(const float* __restrict__ pred,
                                               float* __restrict__ recs) {
  int bt = blockIdx.x;
  int b = bt >> 7;
  float4 v = ((const float4*)(pred + (size_t)b * 512))[threadIdx.x];
  ((float4*)(recs + (size_t)bt * 512))[threadIdx.x] = v;
}

// ------------------------------------------------------------------- host ---
extern "C" void kernel_launch(void* const* d_in, const int* in_sizes, int n_in,
                              void* d_out, int out_size, void* d_ws, size_t ws_size,
                              hipStream_t stream) {
  const float* embed_w = (const float*)d_in[0];
  const float* w_ih = (const float*)d_in[1];
  const float* w_hh = (const float*)d_in[2];
  const float* b_ih = (const float*)d_in[3];
  const float* b_hh = (const float*)d_in[4];
  const float* wz1 = (const float*)d_in[5];
  const float* bz1 = (const float*)d_in[6];
  const float* wz2 = (const float*)d_in[7];
  const float* bz2 = (const float*)d_in[8];
  const float* wb1 = (const float*)d_in[9];
  const float* bb1 = (const float*)d_in[10];
  const float* wb2 = (const float*)d_in[11];
  const float* bb2 = (const float*)d_in[12];
  const float* wd1 = (const float*)d_in[13];
  const float* bd1 = (const float*)d_in[14];
  const float* wd2 = (const float*)d_in[15];
  const float* bd2 = (const float*)d_in[16];
  const int* inputs = (const int*)d_in[17];
  const int* lengths = (const int*)d_in[18];

  char* ws = (char*)d_ws;
  size_t off = 0;
  auto alloc = [&](size_t n) { char* p = ws + off; off += (n + 255) & ~(size_t)255; return p; };
  unsigned short* wih_b = (unsigned short*)alloc((size_t)1024 * 256 * 2);
  unsigned short* wpk   = (unsigned short*)alloc((size_t)1024 * 256 * 2);
  unsigned short* wb1_b = (unsigned short*)alloc((size_t)256 * 256 * 2);
  float* biasg = (float*)alloc(1024 * 4);
  unsigned int* flags = (unsigned int*)alloc(1024 * 4);  // 16 flags, 256B pad
  unsigned short* bufA  = (unsigned short*)alloc((size_t)32768 * 256 * 2);
  unsigned short* enc_b = (unsigned short*)alloc((size_t)32768 * 256 * 2);
  float* lb    = (float*)alloc((size_t)32768 * 4);
  float* lca   = (float*)alloc((size_t)32768 * 4);
  float* maskb = (float*)alloc((size_t)32768 * 4);
  float* rout  = (float*)alloc((size_t)256 * 256 * 4);
  float* zbuf  = (float*)alloc((size_t)256 * 64 * 4);
  float* pred  = (float*)alloc((size_t)256 * 512 * 4);
  size_t fixed = off;
  bool xwf32 = (ws_size >= fixed + (size_t)32768 * 1024 * 4);
  void* xw = alloc(xwf32 ? (size_t)32768 * 1024 * 4 : (size_t)32768 * 1024 * 2);

  unsigned kb[4][2], kz[4][2];
  for (int s = 0; s < 4; ++s) {
    tf2x32(0u, 42u, 0u, (unsigned)(2 * s), &kb[s][0], &kb[s][1]);
    tf2x32(0u, 42u, 0u, (unsigned)(2 * s + 1), &kz[s][0], &kz[s][1]);
  }

  float* out = (float*)d_out;
  float* encs = out;
  float* recs = out + 33554432;
  float* masks = out + 100663296;
  float* blog = out + 100761600;
  float* bsamp = out + 100859904;
  float* zlog = out + 100990976;
  float* zsamp = out + 101122048;

  prep_k<<<256, 256, 0, stream>>>(w_ih, w_hh, wb1, b_ih, b_hh, wih_b, wpk, wb1_b,
                                  biasg, flags);
  embed_k<<<32768, 256, 0, stream>>>(inputs, embed_w, bufA);
  {
    dim3 g(32768 / 128, 1024 / 128);
    gemm_bf16<<<g, 256, 0, stream>>>(bufA, wih_b, biasg,
                                     xwf32 ? (float*)xw : nullptr,
                                     xwf32 ? nullptr : (unsigned short*)xw,
                                     32768, 1024, 256, 0);
  }

  for (int seg = 0; seg < 4; ++seg) {
    unsigned fb = (unsigned)seg * 512u;  // 4 block-increments/rg/step * 128
    if (xwf32)
      lstm_lds<true><<<64, 256, 0, stream>>>(wpk, xw, maskb, seg > 0 ? 1 : 0,
                                             encs + (size_t)seg * 8388608, enc_b,
                                             flags, fb);
    else
      lstm_lds<false><<<64, 256, 0, stream>>>(wpk, xw, maskb, seg > 0 ? 1 : 0,
                                              encs + (size_t)seg * 8388608, enc_b,
                                              flags, fb);

    if (seg < 3) {
      dim3 g(32768 / 128, 256 / 128);
      gemm_bf16<<<g, 256, 0, stream>>>(enc_b, wb1_b, bb1, nullptr, bufA,
                                       32768, 256, 256, 1);
      gemv_lb<<<4096, 512, 0, stream>>>(bufA, wb2, bb2, lb);
      boundary_k<<<256, 128, 0, stream>>>(lb, seg, kb[seg][0], kb[seg][1],
                                          blog + (size_t)seg * 32768,
                                          bsamp + (size_t)seg * 32768,
                                          masks + (size_t)seg * 32768, lca, maskb);
    } else {
      onehot_k<<<256, 128, 0, stream>>>(lengths, bsamp + (size_t)3 * 32768);
    }
    readout_k<<<256, 256, 0, stream>>>(encs + (size_t)seg * 8388608,
                                       bsamp + (size_t)seg * 32768, rout);
    zhead_k<<<256, 128, 0, stream>>>(rout, wz1, bz1, wz2, bz2, kz[seg][0], kz[seg][1],
                                     zlog + (size_t)seg * 32768,
                                     zsamp + (size_t)seg * 16384, zbuf);
    decode_k<<<256, 256, 0, stream>>>(zbuf, wd1, bd1, wd2, bd2, pred);
    bcast_k<<<32768, 128, 0, stream>>>(pred, recs + (size_t)seg * 16777216);
  }
}